// Round 13
// baseline (306.581 us; speedup 1.0000x reference)
//
#include <hip/hip_runtime.h>
#include <hip/hip_bf16.h>
#include <math.h>

// (B,N,C,H,K) = (16,1024,384,6,8), HID=768, HD=64
// R21 = R20 (296us best) with NT=128 -> NT=64 on the FUSED qkv+knn GEMM and fc1.
// Mechanism: those dispatches are latency-bound with Occupancy 23% (LDS 32KB capped
// 5 blocks/CU; ramp/tail dominate at 7.5 blocks/CU of work). NT=64: LDS 24KB ->
// 6 blocks/CU, 2x block count (15/CU of work), half the staging ops per block.
// HBM traffic unchanged (A re-reads hit L2 under chunked swizzle). R7's version of
// this bet was confounded (M-tile halving + VGPR cap); this is the clean test.
#define BN_ROWS 16384
#define CDIM 384
#define NH 6
#define BBATCH 16
#define NNN 1024

typedef unsigned short u16;
typedef unsigned int u32;
typedef __attribute__((ext_vector_type(8))) short short8;
typedef __attribute__((ext_vector_type(4))) float floatx4;

__device__ __forceinline__ float b2f(u16 s) { return __uint_as_float(((u32)s) << 16); }
__device__ __forceinline__ u16 f2b(float f) {
    __hip_bfloat16 h = __float2bfloat16(f);
    u16 s; __builtin_memcpy(&s, &h, 2); return s;
}
// packed bf16 convert (RNE, same as __float2bfloat16): lo -> low16, hi -> high16
__device__ __forceinline__ u32 cvt_pk_bf16(float lo, float hi) {
    u32 r;
    asm("v_cvt_pk_bf16_f32 %0, %1, %2" : "=v"(r) : "v"(lo), "v"(hi));
    return r;
}
__device__ __forceinline__ void gload_lds16(const u16* g, u16* l) {
    __builtin_amdgcn_global_load_lds(
        (const __attribute__((address_space(1))) unsigned int*)g,
        (__attribute__((address_space(3))) unsigned int*)l, 16, 0, 0);
}

// ---------------- fused weight pack: W (KxN fp32) -> Wt (NxK bf16), 6 weights ----------
__global__ __launch_bounds__(256) void pack_all(
    const float* __restrict__ W0, u16* __restrict__ T0,
    const float* __restrict__ W1, u16* __restrict__ T1,
    const float* __restrict__ W2, u16* __restrict__ T2,
    const float* __restrict__ W3, u16* __restrict__ T3,
    const float* __restrict__ W4, u16* __restrict__ T4,
    const float* __restrict__ W5, u16* __restrict__ T5)
{
    const float* W; u16* T; int K, N;
    switch (blockIdx.z) {
        case 0: W = W0; T = T0; K = 384; N = 1152; break;
        case 1: W = W1; T = T1; K = 384; N = 384;  break;
        case 2: W = W2; T = T2; K = 768; N = 384;  break;
        case 3: W = W3; T = T3; K = 768; N = 384;  break;
        case 4: W = W4; T = T4; K = 384; N = 768;  break;
        default: W = W5; T = T5; K = 768; N = 384; break;
    }
    const int n0 = blockIdx.x * 32, k0 = blockIdx.y * 32;
    if (n0 >= N || k0 >= K) return;
    __shared__ float s[32][33];
    const int tx = threadIdx.x & 31, ty = threadIdx.x >> 5;
#pragma unroll
    for (int i = 0; i < 4; ++i)
        s[ty + 8 * i][tx] = W[(size_t)(k0 + ty + 8 * i) * N + n0 + tx];
    __syncthreads();
#pragma unroll
    for (int i = 0; i < 4; ++i)
        T[(size_t)(n0 + ty + 8 * i) * K + k0 + tx] = f2b(s[tx][ty + 8 * i]);
}

// ---------------- LayerNorm: one wave per row; fp32 in, bf16 out ----------------
__global__ __launch_bounds__(64) void ln_kernel(const float* __restrict__ xin,
                                                const float* __restrict__ w,
                                                const float* __restrict__ b,
                                                u16* __restrict__ out)
{
    const int row = blockIdx.x;
    const int t = threadIdx.x;
    const size_t base = (size_t)row * CDIM;
    float v[6];
#pragma unroll
    for (int i = 0; i < 6; ++i) v[i] = xin[base + t + 64 * i];
    float s = 0.f, s2 = 0.f;
#pragma unroll
    for (int i = 0; i < 6; ++i) { s += v[i]; s2 += v[i] * v[i]; }
#pragma unroll
    for (int m = 1; m < 64; m <<= 1) {
        s  += __shfl_xor(s,  m, 64);
        s2 += __shfl_xor(s2, m, 64);
    }
    const float mean = s * (1.0f / CDIM);
    const float var  = s2 * (1.0f / CDIM) - mean * mean;
    const float rs   = rsqrtf(var + 1e-5f);
#pragma unroll
    for (int i = 0; i < 6; ++i) {
        int c = t + 64 * i;
        out[base + c] = f2b((v[i] - mean) * rs * w[c] + b[c]);
    }
}

// ---------------- MFMA GEMM, 2-buffer counted-vmcnt (R18), transposed-C -----------------
// A (MxK bf16) @ Bt^T (Bt is NxK bf16). 128xNT tile, BK=32, 4 waves.
// R10: chunked XCD swizzle. R12: transposed-C epilogue. R13/14: counted-vmcnt 2-deep
// pipeline, raw barriers (proven race-free). 2-buffer LDS: NT=64 -> 24KB (6 blk/CU).
// MODE: 0 normal, 1 qkv head-blocked scatter, 2 split t1/t2,
//       3 FUSED qkv+knn: n-regions [0,1152) qkv-scatter | [1152,1536) t1 |
//         [1536,1920) t2+b_knn (64-aligned -> block-uniform).
template<int ACT, bool HAS_BIAS, bool HAS_RES, bool OUT_F32, int MODE, int NT, bool SWZ>
__global__ __launch_bounds__(256) void gemm_mfma_kernel(
    const u16* __restrict__ A, int lda,
    const u16* __restrict__ Bt, const u16* __restrict__ Bt2, int ldbt,
    u16* Cb, u16* Cb2, u16* Cb3, float* Cf, int ldc,
    const float* __restrict__ bias,
    const float* res,
    int K)
{
    constexpr int NTL = NT / 32;           // n-tiles per wave
    __shared__ u16 As[2][128 * 32];
    __shared__ u16 Bs[2][NT * 32];
    const int tid  = threadIdx.x;
    const int wv   = tid >> 6;
    const int lane = tid & 63;
    const int l15  = lane & 15;
    const int quad = lane >> 4;

    int m0, n0;
    if (SWZ) {
        const int nbx = gridDim.x;
        const int total = nbx * gridDim.y;
        int lin = blockIdx.x + nbx * blockIdx.y;
        const int cpx = total >> 3;
        lin = (lin & 7) * cpx + (lin >> 3);
        m0 = (lin / nbx) * 128;
        n0 = (lin % nbx) * NT;
    } else {
        m0 = blockIdx.y * 128;
        n0 = blockIdx.x * NT;
    }

    const int woffm = (wv >> 1) * 64;
    const int woffn = (wv & 1) * (NT / 2);

    // B-source routing (block-uniform)
    const u16* bsrc; int brow0, koff, bld;
    if constexpr (MODE == 3) {
        if (n0 < 1152)      { bsrc = Bt;  brow0 = n0;        koff = 0;   bld = 384; }
        else if (n0 < 1536) { bsrc = Bt2; brow0 = n0 - 1152; koff = 0;   bld = 768; }
        else                { bsrc = Bt2; brow0 = n0 - 1536; koff = 384; bld = 768; }
    } else {
        bsrc  = (MODE == 2 && n0 >= 384) ? Bt2 : Bt;
        brow0 = (MODE == 2 && n0 >= 384) ? (n0 - 384) : n0;
        koff = 0; bld = ldbt;
    }

    floatx4 acc[4][NTL];
#pragma unroll
    for (int mt = 0; mt < 4; ++mt)
#pragma unroll
        for (int nt = 0; nt < NTL; ++nt) acc[mt][nt] = (floatx4){0.f, 0.f, 0.f, 0.f};

    const int gsw  = 8 * ((lane & 3) ^ ((lane >> 3) & 3));  // fetch-granule swizzle
    const int rloc = lane >> 2;                              // row within 16-row slab
    const int rdsw = 8 * (quad ^ ((l15 >> 1) & 3));          // read-granule swizzle

    auto stage = [&](int kt, int p) {
#pragma unroll
        for (int j = 0; j < 2; ++j) {
            const int slab = 32 * wv + 16 * j;
            gload_lds16(A + (size_t)(m0 + slab + rloc) * lda + kt + gsw, &As[p][slab * 32]);
        }
        if (NT == 128) {
#pragma unroll
            for (int j = 0; j < 2; ++j) {
                const int slab = 32 * wv + 16 * j;
                gload_lds16(bsrc + (size_t)(brow0 + slab + rloc) * bld + koff + kt + gsw,
                            &Bs[p][slab * 32]);
            }
        } else {
            const int slab = 16 * wv;
            gload_lds16(bsrc + (size_t)(brow0 + slab + rloc) * bld + koff + kt + gsw,
                        &Bs[p][slab * 32]);
        }
    };

    stage(0, 0);
    stage(32, 1);
    int cur = 0;
    for (int kt = 0; kt < K; kt += 32) {
        if (kt + 32 < K) {
            if constexpr (NT == 128) asm volatile("s_waitcnt vmcnt(4)" ::: "memory");
            else                     asm volatile("s_waitcnt vmcnt(3)" ::: "memory");
        } else {
            asm volatile("s_waitcnt vmcnt(0)" ::: "memory");
        }
        __builtin_amdgcn_sched_barrier(0);
        __builtin_amdgcn_s_barrier();          // buf[cur] visible to all waves
        __builtin_amdgcn_sched_barrier(0);

        short8 af[4], bf[NTL];
#pragma unroll
        for (int mt = 0; mt < 4; ++mt)
            af[mt] = *(const short8*)(As[cur] + (woffm + mt * 16 + l15) * 32 + rdsw);
#pragma unroll
        for (int nt = 0; nt < NTL; ++nt)
            bf[nt] = *(const short8*)(Bs[cur] + (woffn + nt * 16 + l15) * 32 + rdsw);
#pragma unroll
        for (int mt = 0; mt < 4; ++mt)
#pragma unroll
            for (int nt = 0; nt < NTL; ++nt)
                acc[mt][nt] = __builtin_amdgcn_mfma_f32_16x16x32_bf16(
                    bf[nt], af[mt], acc[mt][nt], 0, 0, 0);
        __builtin_amdgcn_sched_barrier(0);
        __builtin_amdgcn_s_barrier();          // all waves done reading buf[cur]
        __builtin_amdgcn_sched_barrier(0);
        if (kt + 64 < K) stage(kt + 64, cur);  // async refill; waited 2 iters later
        cur ^= 1;
    }

    // epilogue (transposed-C): lane holds rows gr = ..+l15, cols gc0..gc0+3
#pragma unroll
    for (int mt = 0; mt < 4; ++mt) {
        const int gr = m0 + woffm + mt * 16 + l15;
#pragma unroll
        for (int nt = 0; nt < NTL; ++nt) {
            const int gc0 = n0 + woffn + nt * 16 + quad * 4;
            float v4[4];
#pragma unroll
            for (int rr = 0; rr < 4; ++rr) v4[rr] = acc[mt][nt][rr];
            if (HAS_BIAS) {
                const floatx4 bv = *(const floatx4*)(bias + gc0);
#pragma unroll
                for (int rr = 0; rr < 4; ++rr) v4[rr] += bv[rr];
            }
            if (MODE == 2 && gc0 >= 384) {
                const floatx4 bv = *(const floatx4*)(bias + gc0 - 384);
#pragma unroll
                for (int rr = 0; rr < 4; ++rr) v4[rr] += bv[rr];
            }
            if (MODE == 3 && gc0 >= 1536) {    // t2 region gets b_knn
                const floatx4 bv = *(const floatx4*)(bias + gc0 - 1536);
#pragma unroll
                for (int rr = 0; rr < 4; ++rr) v4[rr] += bv[rr];
            }
            if (ACT == 1) {
#pragma unroll
                for (int rr = 0; rr < 4; ++rr)
                    v4[rr] = 0.5f * v4[rr] * (1.0f + erff(v4[rr] * 0.70710678118654752f));
            }
            if (HAS_RES) {
                const floatx4 rv = *(const floatx4*)(res + (size_t)gr * ldc + gc0);
#pragma unroll
                for (int rr = 0; rr < 4; ++rr) v4[rr] += rv[rr];
            }
            if (MODE == 1 || (MODE == 3 && gc0 < 1152)) {
                const int t3  = gc0 / 384;
                const int rem = gc0 - t3 * 384;
                const int hh = rem >> 6, dd = rem & 63;
                const int bb = gr >> 10, nn = gr & 1023;
                u32 lo = cvt_pk_bf16(v4[0], v4[1]);
                u32 hi = cvt_pk_bf16(v4[2], v4[3]);
                *(uint2*)(Cb + ((size_t)((bb * 6 + hh) * 1024 + nn)) * 192 + t3 * 64 + dd) =
                    make_uint2(lo, hi);
            } else if (MODE == 3) {
                u32 lo = cvt_pk_bf16(v4[0], v4[1]);
                u32 hi = cvt_pk_bf16(v4[2], v4[3]);
                if (gc0 < 1536)
                    *(uint2*)(Cb2 + (size_t)gr * 384 + gc0 - 1152) = make_uint2(lo, hi);
                else
                    *(uint2*)(Cb3 + (size_t)gr * 384 + gc0 - 1536) = make_uint2(lo, hi);
            } else if (MODE == 2) {
                u32 lo = cvt_pk_bf16(v4[0], v4[1]);
                u32 hi = cvt_pk_bf16(v4[2], v4[3]);
                if (gc0 < 384)
                    *(uint2*)(Cb  + (size_t)gr * 384 + gc0)       = make_uint2(lo, hi);
                else
                    *(uint2*)(Cb2 + (size_t)gr * 384 + gc0 - 384) = make_uint2(lo, hi);
            } else if (OUT_F32) {
                floatx4 vv = {v4[0], v4[1], v4[2], v4[3]};
                *(floatx4*)(Cf + (size_t)gr * ldc + gc0) = vv;
            } else {
                u32 lo = cvt_pk_bf16(v4[0], v4[1]);
                u32 hi = cvt_pk_bf16(v4[2], v4[3]);
                *(uint2*)(Cb + (size_t)gr * ldc + gc0) = make_uint2(lo, hi);
            }
        }
    }
}

// ---------------- R20: proj GEMM + knnmax merged into one heterogeneous dispatch --------
// blocks [0, 768): proj = aout @ wprojT + bproj -> x1cat cols 0..383 (ld 768).
// blocks [768, 768+4096): knnmax, 4 rows/block (wave w -> row kb*4+w, lanes 0..47).
__global__ __launch_bounds__(256) void projknn_kernel(
    const u16* __restrict__ A,              // aout
    const u16* __restrict__ Bt,             // wprojT (384x384, ld 384)
    const float* __restrict__ bias,         // bproj
    const u16* __restrict__ t1,
    const u16* __restrict__ t2,
    const int* __restrict__ idx,
    u16* __restrict__ x1cat)
{
    constexpr int GB = 768;                 // GEMM blocks: (6 n) x (128 m)
    __shared__ u16 As[2][128 * 32];
    __shared__ u16 Bs[2][64 * 32];
    const int tid  = threadIdx.x;
    const int lane = tid & 63;

    if (blockIdx.x >= GB) {
        // ---------------- knnmax path ----------------
        const int bn = (blockIdx.x - GB) * 4 + (tid >> 6);
        if (lane >= 48) return;
        const int b = bn >> 10, n = bn & 1023;
        int ind[8];
#pragma unroll
        for (int k = 0; k < 8; ++k) ind[k] = idx[b * 8192 + k * 1024 + n];
        const int c0 = lane * 8;
        const size_t rbase = (size_t)bn * CDIM + c0;
        short8 v1 = *(const short8*)(t1 + rbase);
        short8 v2 = *(const short8*)(t2 + rbase);
        float basef[8], mx[8];
#pragma unroll
        for (int j = 0; j < 8; ++j) {
            basef[j] = b2f((u16)v2[j]) - b2f((u16)v1[j]);
            mx[j] = -1e30f;
        }
#pragma unroll
        for (int k = 0; k < 8; ++k) {
            short8 nv = *(const short8*)(t1 + (size_t)ind[k] * CDIM + c0);
#pragma unroll
            for (int j = 0; j < 8; ++j) {
                float v = b2f((u16)nv[j]) + basef[j];
                v = (v > 0.f) ? v : 0.2f * v;
                mx[j] = fmaxf(mx[j], v);
            }
        }
        short8 ov;
#pragma unroll
        for (int j = 0; j < 8; ++j) ov[j] = (short)f2b(mx[j]);
        *(short8*)(x1cat + (size_t)bn * 768 + CDIM + c0) = ov;
        return;
    }

    // ---------------- proj GEMM path (NT=64, MODE 0, bias, bf16 out ld 768) ----------
    const int wv   = tid >> 6;
    const int l15  = lane & 15;
    const int quad = lane >> 4;
    int lin = blockIdx.x;                   // [0, 768): chunked swizzle, cpx = 96
    lin = (lin & 7) * 96 + (lin >> 3);
    const int m0 = (lin / 6) * 128;
    const int n0 = (lin % 6) * 64;
    const int woffm = (wv >> 1) * 64;
    const int woffn = (wv & 1) * 32;

    floatx4 acc[4][2];
#pragma unroll
    for (int mt = 0; mt < 4; ++mt)
#pragma unroll
        for (int nt = 0; nt < 2; ++nt) acc[mt][nt] = (floatx4){0.f, 0.f, 0.f, 0.f};

    const int gsw  = 8 * ((lane & 3) ^ ((lane >> 3) & 3));
    const int rloc = lane >> 2;
    const int rdsw = 8 * (quad ^ ((l15 >> 1) & 3));

    auto stage = [&](int kt, int p) {
#pragma unroll
        for (int j = 0; j < 2; ++j) {
            const int slab = 32 * wv + 16 * j;
            gload_lds16(A + (size_t)(m0 + slab + rloc) * CDIM + kt + gsw, &As[p][slab * 32]);
        }
        const int slab = 16 * wv;
        gload_lds16(Bt + (size_t)(n0 + slab + rloc) * CDIM + kt + gsw, &Bs[p][slab * 32]);
    };

    stage(0, 0);
    stage(32, 1);
    int cur = 0;
    for (int kt = 0; kt < CDIM; kt += 32) {
        if (kt + 32 < CDIM) asm volatile("s_waitcnt vmcnt(3)" ::: "memory");
        else                asm volatile("s_waitcnt vmcnt(0)" ::: "memory");
        __builtin_amdgcn_sched_barrier(0);
        __builtin_amdgcn_s_barrier();
        __builtin_amdgcn_sched_barrier(0);

        short8 af[4], bf[2];
#pragma unroll
        for (int mt = 0; mt < 4; ++mt)
            af[mt] = *(const short8*)(As[cur] + (woffm + mt * 16 + l15) * 32 + rdsw);
#pragma unroll
        for (int nt = 0; nt < 2; ++nt)
            bf[nt] = *(const short8*)(Bs[cur] + (woffn + nt * 16 + l15) * 32 + rdsw);
#pragma unroll
        for (int mt = 0; mt < 4; ++mt)
#pragma unroll
            for (int nt = 0; nt < 2; ++nt)
                acc[mt][nt] = __builtin_amdgcn_mfma_f32_16x16x32_bf16(
                    bf[nt], af[mt], acc[mt][nt], 0, 0, 0);
        __builtin_amdgcn_sched_barrier(0);
        __builtin_amdgcn_s_barrier();
        __builtin_amdgcn_sched_barrier(0);
        if (kt + 64 < CDIM) stage(kt + 64, cur);
        cur ^= 1;
    }

#pragma unroll
    for (int mt = 0; mt < 4; ++mt) {
        const int gr = m0 + woffm + mt * 16 + l15;
#pragma unroll
        for (int nt = 0; nt < 2; ++nt) {
            const int gc0 = n0 + woffn + nt * 16 + quad * 4;
            const floatx4 bv = *(const floatx4*)(bias + gc0);
            float v4[4];
#pragma unroll
            for (int rr = 0; rr < 4; ++rr) v4[rr] = acc[mt][nt][rr] + bv[rr];
            u32 lo = cvt_pk_bf16(v4[0], v4[1]);
            u32 hi = cvt_pk_bf16(v4[2], v4[3]);
            *(uint2*)(x1cat + (size_t)gr * 768 + gc0) = make_uint2(lo, hi);
        }
    }
}

// ---------------- MFMA flash attention (R17: MFMA rowsum, T14 async-stage) --------------
__global__ __launch_bounds__(256) void attn_mfma_kernel(const u16* __restrict__ qkv2,
                                                        u16* __restrict__ aout)
{
    const int id = blockIdx.x;
    const int rxcd = id & 7;
    const int j = id >> 3;
    const int slab = rxcd + 8 * (j % 12);
    const int qtile = j / 12;
    const int b = slab / NH, h = slab % NH;

    const int wave = threadIdx.x >> 6;
    const int lane = threadIdx.x & 63;
    const int l15 = lane & 15;
    const int quad = lane >> 4;
    const int qbase = qtile * 128 + wave * 32;
    const int tid = threadIdx.x;

    const u16* slabp = qkv2 + ((size_t)(b * NH + h) << 10) * 192;

    __shared__ __align__(16) u16 Ks[64 * 72];
    __shared__ __align__(16) u16 Vt[64 * 72];
    __shared__ __align__(16) u16 Ps[4][32 * 72];

    short8 qf[2][2];
#pragma unroll
    for (int nt = 0; nt < 2; ++nt) {
        const u16* qrow = slabp + (size_t)(qbase + nt * 16 + l15) * 192;
        qf[nt][0] = *(const short8*)(qrow + quad * 8);
        qf[nt][1] = *(const short8*)(qrow + 32 + quad * 8);
    }

    short8 vones;
#pragma unroll
    for (int i = 0; i < 8; ++i) vones[i] = (l15 == 0) ? (short)0x3F80 : (short)0;

    floatx4 Oacc[2][4];
    floatx4 rAcc[2];
#pragma unroll
    for (int mt = 0; mt < 2; ++mt) {
        rAcc[mt] = (floatx4){0.f, 0.f, 0.f, 0.f};
#pragma unroll
        for (int nt = 0; nt < 4; ++nt) Oacc[mt][nt] = (floatx4){0.f, 0.f, 0.f, 0.f};
    }

    const int key = tid >> 2, dblk = (tid & 3) * 16;
    const int kp2 = tid & 31, db = (tid >> 5) * 8;
    uint4 kr0, kr1, vr0, vr1;
    {
        const u16* kp = slabp + (size_t)key * 192 + 64 + dblk;
        kr0 = *(const uint4*)(kp);
        kr1 = *(const uint4*)(kp + 8);
        const u16* vp = slabp + (size_t)(2 * kp2) * 192 + 128 + db;
        vr0 = *(const uint4*)(vp);
        vr1 = *(const uint4*)(vp + 192);
    }

    for (int kc = 0; kc < NNN; kc += 64) {
        *(uint4*)(Ks + key * 72 + dblk)     = kr0;
        *(uint4*)(Ks + key * 72 + dblk + 8) = kr1;
        {
            u32 a0[4] = {vr0.x, vr0.y, vr0.z, vr0.w};
            u32 a1[4] = {vr1.x, vr1.y, vr1.z, vr1.w};
#pragma unroll
            for (int i = 0; i < 4; ++i) {
                u32 lo = __builtin_amdgcn_perm(a1[i], a0[i], 0x05040100u);
                u32 hi = __builtin_amdgcn_perm(a1[i], a0[i], 0x07060302u);
                *(u32*)(Vt + (size_t)(db + 2 * i)     * 72 + 2 * kp2) = lo;
                *(u32*)(Vt + (size_t)(db + 2 * i + 1) * 72 + 2 * kp2) = hi;
            }
        }
        __syncthreads();

        if (kc + 64 < NNN) {
            const u16* kp = slabp + (size_t)(kc + 64 + key) * 192 + 64 + dblk;
            kr0 = *(const uint4*)(kp);
            kr1 = *(const uint4*)(kp + 8);
            const u16* vp = slabp + (size_t)(kc + 64 + 2 * kp2) * 192 + 128 + db;
            vr0 = *(const uint4*)(vp);
            vr1 = *(const uint4*)(vp + 192);
        }

        floatx4 sc[4][2];
        __builtin_amdgcn_s_setprio(1);
#pragma unroll
        for (int kt_ = 0; kt_ < 4; ++kt_) {
            short8 kf0 = *(const short8*)(Ks + (kt_ * 16 + l15) * 72 + quad * 8);
            short8 kf1 = *(const short8*)(Ks + (kt_ * 16 + l15) * 72 + 32 + quad * 8);
#pragma unroll
            for (int nt = 0; nt < 2; ++nt) {
                floatx4 s = {0.f, 0.f, 0.f, 0.f};
                s = __builtin_amdgcn_mfma_f32_16x16x32_bf16(kf0, qf[nt][0], s, 0, 0, 0);
                s = __builtin_amdgcn_mfma_f32_16x16x32_bf16(kf1, qf[nt][1], s, 0, 0, 0);
                sc[kt_][nt] = s;
            }
        }
        __builtin_amdgcn_s_setprio(0);

#pragma unroll
        for (int kt_ = 0; kt_ < 4; ++kt_)
#pragma unroll
            for (int nt = 0; nt < 2; ++nt) {
                float pv[4];
#pragma unroll
                for (int rr = 0; rr < 4; ++rr)
                    pv[rr] = __expf(sc[kt_][nt][rr] * 0.125f);
                u32 lo = cvt_pk_bf16(pv[0], pv[1]);
                u32 hi = cvt_pk_bf16(pv[2], pv[3]);
                *(uint2*)(Ps[wave] + (nt * 16 + l15) * 72 + kt_ * 16 + quad * 4) =
                    make_uint2(lo, hi);
            }

        short8 pf[2][2];
#pragma unroll
        for (int mt = 0; mt < 2; ++mt) {
            pf[mt][0] = *(const short8*)(Ps[wave] + (mt * 16 + l15) * 72 + quad * 8);
            pf[mt][1] = *(const short8*)(Ps[wave] + (mt * 16 + l15) * 72 + 32 + quad * 8);
        }
        __builtin_amdgcn_s_setprio(1);
#pragma unroll
        for (int mt = 0; mt < 2; ++mt) {
            rAcc[mt] = __builtin_amdgcn_mfma_f32_16x16x32_bf16(pf[mt][0], vones, rAcc[mt], 0, 0, 0);
            rAcc[mt] = __builtin_amdgcn_mfma_f32_16x16x32_bf16(pf[mt][1], vones, rAcc[mt], 0, 0, 0);
        }
#pragma unroll
        for (int nt = 0; nt < 4; ++nt) {
#pragma unroll
            for (int kk = 0; kk < 2; ++kk) {
                short8 vf = *(const short8*)(Vt + (size_t)(nt * 16 + l15) * 72 + kk * 32 + quad * 8);
#pragma unroll
                for (int mt = 0; mt < 2; ++mt)
                    Oacc[mt][nt] = __builtin_amdgcn_mfma_f32_16x16x32_bf16(
                        pf[mt][kk], vf, Oacc[mt][nt], 0, 0, 0);
            }
        }
        __builtin_amdgcn_s_setprio(0);
        __syncthreads();
    }

#pragma unroll
    for (int mt = 0; mt < 2; ++mt) {
#pragma unroll
        for (int rr = 0; rr < 4; ++rr) {
            float l = __shfl(rAcc[mt][rr], quad << 4, 64);
            float inv = 1.0f / l;
            int q = qbase + mt * 16 + quad * 4 + rr;
#pragma unroll
            for (int nt = 0; nt < 4; ++nt)
                aout[(size_t)(b * NNN + q) * CDIM + h * 64 + nt * 16 + l15] =
                    f2b(Oacc[mt][nt][rr] * inv);
        }
    }
}

extern "C" void kernel_launch(void* const* d_in, const int* in_sizes, int n_in,
                              void* d_out, int out_size, void* d_ws, size_t ws_size,
                              hipStream_t stream)
{
    (void)in_sizes; (void)n_in; (void)out_size; (void)ws_size;
    const float* x     = (const float*)d_in[0];
    const int*   knn   = (const int*)d_in[1];
    const float* ln1w  = (const float*)d_in[2];
    const float* ln1b  = (const float*)d_in[3];
    const float* wqkv  = (const float*)d_in[4];
    const float* wproj = (const float*)d_in[5];
    const float* bproj = (const float*)d_in[6];
    const float* wknn  = (const float*)d_in[7];
    const float* bknn  = (const float*)d_in[8];
    const float* wmrg  = (const float*)d_in[9];
    const float* bmrg  = (const float*)d_in[10];
    const float* ln2w  = (const float*)d_in[11];
    const float* ln2b  = (const float*)d_in[12];
    const float* wfc1  = (const float*)d_in[13];
    const float* bfc1  = (const float*)d_in[14];
    const float* wfc2  = (const float*)d_in[15];
    const float* bfc2  = (const float*)d_in[16];

    u16* wsb = (u16*)d_ws;
    const size_t RE = (size_t)BN_ROWS * CDIM;
    // buffer plan (stream-ordered reuse):
    u16* nxb   = wsb;                      // ln1 out; dead after FUSED
    u16* qkvb  = wsb + RE;                 // 3RE; dead after attn
    u16* aoutb = wsb;                      // attn out (over nx)
    u16* x1cat = wsb + RE;                 // projknn out (over qkv)
    u16* hinb  = wsb;                      // ln2 out (over aout)
    u16* h1b   = wsb + RE;                 // fc1 out (over x1cat)
    u16* t1b   = (u16*)d_out;              // FUSED out; dead after projknn
    u16* t2b   = (u16*)d_out + RE;         // FUSED out; dead after projknn
    float* xmid = (float*)d_out;           // merge out (over t1/t2); fc2 res + final out
    u16* wqkvT  = wsb + 4 * RE;            // 1152 x 384
    u16* wprojT = wqkvT + 442368;          // 384 x 384
    u16* wknnT  = wprojT + 147456;         // 384 x 768 (two K-halves)
    u16* wmrgT  = wknnT + 294912;          // 384 x 768
    u16* wfc1T  = wmrgT + 294912;          // 768 x 384
    u16* wfc2T  = wfc1T + 294912;          // 384 x 768

    // 0) pack all weights -> bf16 transposed (one launch)
    pack_all<<<dim3(36, 24, 6), 256, 0, stream>>>(
        wqkv, wqkvT, wproj, wprojT, wknn, wknnT, wmrg, wmrgT, wfc1, wfc1T, wfc2, wfc2T);
    // 1) nx = LN1(x)
    ln_kernel<<<BN_ROWS, 64, 0, stream>>>(x, ln1w, ln1b, nxb);
    // 2) FUSED qkv+knn: [qkv scatter | t1 | t2+b_knn], N=1920, NT=64, grid (30,128)
    gemm_mfma_kernel<0, false, false, false, 3, 64, true><<<dim3(30, 128), 256, 0, stream>>>(
        nxb, CDIM, wqkvT, wknnT, 384, qkvb, t1b, t2b, nullptr, 0, bknn, nullptr, CDIM);
    // 3) attention -> aout (over nx)
    attn_mfma_kernel<<<768, 256, 0, stream>>>(qkvb, aoutb);
    // 4+5) proj GEMM + knnmax in ONE dispatch (independent; writes x1cat halves)
    projknn_kernel<<<768 + BN_ROWS / 4, 256, 0, stream>>>(
        aoutb, wprojT, bproj, t1b, t2b, knn, x1cat);
    // 6) xmid = x1cat @ w_merge + b_merge + x -> fp32 d_out (t1/t2 dead)
    gemm_mfma_kernel<0, true, true, true, 0, 64, true><<<dim3(6, 128), 256, 0, stream>>>(
        x1cat, 768, wmrgT, nullptr, 768, nullptr, nullptr, nullptr, xmid, CDIM, bmrg, x, 768);
    // 7) hin = LN2(xmid)
    ln_kernel<<<BN_ROWS, 64, 0, stream>>>(xmid, ln2w, ln2b, hinb);
    // 8) h1 = gelu(hin @ w_fc1 + b_fc1) [NT=64, grid (12,128)]
    gemm_mfma_kernel<1, true, false, false, 0, 64, true><<<dim3(12, 128), 256, 0, stream>>>(
        hinb, CDIM, wfc1T, nullptr, CDIM, h1b, nullptr, nullptr, nullptr, 768, bfc1, nullptr, CDIM);
    // 9) out = h1 @ w_fc2 + b_fc2 + xmid (in-place fp32 per-element)
    gemm_mfma_kernel<0, true, true, true, 0, 64, true><<<dim3(6, 128), 256, 0, stream>>>(
        h1b, 768, wfc2T, nullptr, 768, nullptr, nullptr, nullptr, (float*)d_out, CDIM, bfc2, xmid, 768);
}

// Round 14
// 296.612 us; speedup vs baseline: 1.0336x; 1.0336x over previous
//
#include <hip/hip_runtime.h>
#include <hip/hip_bf16.h>
#include <math.h>

// (B,N,C,H,K) = (16,1024,384,6,8), HID=768, HD=64
// R22 = R20 byte-identical revert (session best: 296.2us). R21's NT=64 on the fused
// GEMM + fc1 DOUBLED occupancy (23->48%) yet regressed both (54->60us; total +10.3)
// -- occupancy definitively not the constraint; per-block staging efficiency is.
// Final configuration: LDS-staged GEMM (2-buffer counted-vmcnt, NT=128 fused/fc1,
// NT=64 narrow), transposed-C epilogue, chunked XCD swizzle, qkv+knn MODE=3 fusion,
// proj+knnmax heterogeneous merge, attn MFMA-rowsum + T14 async-stage.
#define BN_ROWS 16384
#define CDIM 384
#define NH 6
#define BBATCH 16
#define NNN 1024

typedef unsigned short u16;
typedef unsigned int u32;
typedef __attribute__((ext_vector_type(8))) short short8;
typedef __attribute__((ext_vector_type(4))) float floatx4;

__device__ __forceinline__ float b2f(u16 s) { return __uint_as_float(((u32)s) << 16); }
__device__ __forceinline__ u16 f2b(float f) {
    __hip_bfloat16 h = __float2bfloat16(f);
    u16 s; __builtin_memcpy(&s, &h, 2); return s;
}
// packed bf16 convert (RNE, same as __float2bfloat16): lo -> low16, hi -> high16
__device__ __forceinline__ u32 cvt_pk_bf16(float lo, float hi) {
    u32 r;
    asm("v_cvt_pk_bf16_f32 %0, %1, %2" : "=v"(r) : "v"(lo), "v"(hi));
    return r;
}
__device__ __forceinline__ void gload_lds16(const u16* g, u16* l) {
    __builtin_amdgcn_global_load_lds(
        (const __attribute__((address_space(1))) unsigned int*)g,
        (__attribute__((address_space(3))) unsigned int*)l, 16, 0, 0);
}

// ---------------- fused weight pack: W (KxN fp32) -> Wt (NxK bf16), 6 weights ----------
__global__ __launch_bounds__(256) void pack_all(
    const float* __restrict__ W0, u16* __restrict__ T0,
    const float* __restrict__ W1, u16* __restrict__ T1,
    const float* __restrict__ W2, u16* __restrict__ T2,
    const float* __restrict__ W3, u16* __restrict__ T3,
    const float* __restrict__ W4, u16* __restrict__ T4,
    const float* __restrict__ W5, u16* __restrict__ T5)
{
    const float* W; u16* T; int K, N;
    switch (blockIdx.z) {
        case 0: W = W0; T = T0; K = 384; N = 1152; break;
        case 1: W = W1; T = T1; K = 384; N = 384;  break;
        case 2: W = W2; T = T2; K = 768; N = 384;  break;
        case 3: W = W3; T = T3; K = 768; N = 384;  break;
        case 4: W = W4; T = T4; K = 384; N = 768;  break;
        default: W = W5; T = T5; K = 768; N = 384; break;
    }
    const int n0 = blockIdx.x * 32, k0 = blockIdx.y * 32;
    if (n0 >= N || k0 >= K) return;
    __shared__ float s[32][33];
    const int tx = threadIdx.x & 31, ty = threadIdx.x >> 5;
#pragma unroll
    for (int i = 0; i < 4; ++i)
        s[ty + 8 * i][tx] = W[(size_t)(k0 + ty + 8 * i) * N + n0 + tx];
    __syncthreads();
#pragma unroll
    for (int i = 0; i < 4; ++i)
        T[(size_t)(n0 + ty + 8 * i) * K + k0 + tx] = f2b(s[tx][ty + 8 * i]);
}

// ---------------- LayerNorm: one wave per row; fp32 in, bf16 out ----------------
__global__ __launch_bounds__(64) void ln_kernel(const float* __restrict__ xin,
                                                const float* __restrict__ w,
                                                const float* __restrict__ b,
                                                u16* __restrict__ out)
{
    const int row = blockIdx.x;
    const int t = threadIdx.x;
    const size_t base = (size_t)row * CDIM;
    float v[6];
#pragma unroll
    for (int i = 0; i < 6; ++i) v[i] = xin[base + t + 64 * i];
    float s = 0.f, s2 = 0.f;
#pragma unroll
    for (int i = 0; i < 6; ++i) { s += v[i]; s2 += v[i] * v[i]; }
#pragma unroll
    for (int m = 1; m < 64; m <<= 1) {
        s  += __shfl_xor(s,  m, 64);
        s2 += __shfl_xor(s2, m, 64);
    }
    const float mean = s * (1.0f / CDIM);
    const float var  = s2 * (1.0f / CDIM) - mean * mean;
    const float rs   = rsqrtf(var + 1e-5f);
#pragma unroll
    for (int i = 0; i < 6; ++i) {
        int c = t + 64 * i;
        out[base + c] = f2b((v[i] - mean) * rs * w[c] + b[c]);
    }
}

// ---------------- MFMA GEMM, 2-buffer counted-vmcnt (R18), transposed-C -----------------
// A (MxK bf16) @ Bt^T (Bt is NxK bf16). 128xNT tile, BK=32, 4 waves.
// R10: chunked XCD swizzle. R12: transposed-C epilogue. R13/14: counted-vmcnt 2-deep
// pipeline, raw barriers (proven race-free). 2-buffer LDS: NT=128 -> 32KB.
// MODE: 0 normal, 1 qkv head-blocked scatter, 2 split t1/t2,
//       3 FUSED qkv+knn: n-regions [0,1152) qkv-scatter | [1152,1536) t1 |
//         [1536,1920) t2+b_knn.
template<int ACT, bool HAS_BIAS, bool HAS_RES, bool OUT_F32, int MODE, int NT, bool SWZ>
__global__ __launch_bounds__(256) void gemm_mfma_kernel(
    const u16* __restrict__ A, int lda,
    const u16* __restrict__ Bt, const u16* __restrict__ Bt2, int ldbt,
    u16* Cb, u16* Cb2, u16* Cb3, float* Cf, int ldc,
    const float* __restrict__ bias,
    const float* res,
    int K)
{
    constexpr int NTL = NT / 32;           // n-tiles per wave
    __shared__ u16 As[2][128 * 32];
    __shared__ u16 Bs[2][NT * 32];
    const int tid  = threadIdx.x;
    const int wv   = tid >> 6;
    const int lane = tid & 63;
    const int l15  = lane & 15;
    const int quad = lane >> 4;

    int m0, n0;
    if (SWZ) {
        const int nbx = gridDim.x;
        const int total = nbx * gridDim.y;
        int lin = blockIdx.x + nbx * blockIdx.y;
        const int cpx = total >> 3;
        lin = (lin & 7) * cpx + (lin >> 3);
        m0 = (lin / nbx) * 128;
        n0 = (lin % nbx) * NT;
    } else {
        m0 = blockIdx.y * 128;
        n0 = blockIdx.x * NT;
    }

    const int woffm = (wv >> 1) * 64;
    const int woffn = (wv & 1) * (NT / 2);

    // B-source routing (block-uniform)
    const u16* bsrc; int brow0, koff, bld;
    if constexpr (MODE == 3) {
        if (n0 < 1152)      { bsrc = Bt;  brow0 = n0;        koff = 0;   bld = 384; }
        else if (n0 < 1536) { bsrc = Bt2; brow0 = n0 - 1152; koff = 0;   bld = 768; }
        else                { bsrc = Bt2; brow0 = n0 - 1536; koff = 384; bld = 768; }
    } else {
        bsrc  = (MODE == 2 && n0 >= 384) ? Bt2 : Bt;
        brow0 = (MODE == 2 && n0 >= 384) ? (n0 - 384) : n0;
        koff = 0; bld = ldbt;
    }

    floatx4 acc[4][NTL];
#pragma unroll
    for (int mt = 0; mt < 4; ++mt)
#pragma unroll
        for (int nt = 0; nt < NTL; ++nt) acc[mt][nt] = (floatx4){0.f, 0.f, 0.f, 0.f};

    const int gsw  = 8 * ((lane & 3) ^ ((lane >> 3) & 3));  // fetch-granule swizzle
    const int rloc = lane >> 2;                              // row within 16-row slab
    const int rdsw = 8 * (quad ^ ((l15 >> 1) & 3));          // read-granule swizzle

    auto stage = [&](int kt, int p) {
#pragma unroll
        for (int j = 0; j < 2; ++j) {
            const int slab = 32 * wv + 16 * j;
            gload_lds16(A + (size_t)(m0 + slab + rloc) * lda + kt + gsw, &As[p][slab * 32]);
        }
        if (NT == 128) {
#pragma unroll
            for (int j = 0; j < 2; ++j) {
                const int slab = 32 * wv + 16 * j;
                gload_lds16(bsrc + (size_t)(brow0 + slab + rloc) * bld + koff + kt + gsw,
                            &Bs[p][slab * 32]);
            }
        } else {
            const int slab = 16 * wv;
            gload_lds16(bsrc + (size_t)(brow0 + slab + rloc) * bld + koff + kt + gsw,
                        &Bs[p][slab * 32]);
        }
    };

    stage(0, 0);
    stage(32, 1);
    int cur = 0;
    for (int kt = 0; kt < K; kt += 32) {
        if (kt + 32 < K) {
            if constexpr (NT == 128) asm volatile("s_waitcnt vmcnt(4)" ::: "memory");
            else                     asm volatile("s_waitcnt vmcnt(3)" ::: "memory");
        } else {
            asm volatile("s_waitcnt vmcnt(0)" ::: "memory");
        }
        __builtin_amdgcn_sched_barrier(0);
        __builtin_amdgcn_s_barrier();          // buf[cur] visible to all waves
        __builtin_amdgcn_sched_barrier(0);

        short8 af[4], bf[NTL];
#pragma unroll
        for (int mt = 0; mt < 4; ++mt)
            af[mt] = *(const short8*)(As[cur] + (woffm + mt * 16 + l15) * 32 + rdsw);
#pragma unroll
        for (int nt = 0; nt < NTL; ++nt)
            bf[nt] = *(const short8*)(Bs[cur] + (woffn + nt * 16 + l15) * 32 + rdsw);
#pragma unroll
        for (int mt = 0; mt < 4; ++mt)
#pragma unroll
            for (int nt = 0; nt < NTL; ++nt)
                acc[mt][nt] = __builtin_amdgcn_mfma_f32_16x16x32_bf16(
                    bf[nt], af[mt], acc[mt][nt], 0, 0, 0);
        __builtin_amdgcn_sched_barrier(0);
        __builtin_amdgcn_s_barrier();          // all waves done reading buf[cur]
        __builtin_amdgcn_sched_barrier(0);
        if (kt + 64 < K) stage(kt + 64, cur);  // async refill; waited 2 iters later
        cur ^= 1;
    }

    // epilogue (transposed-C): lane holds rows gr = ..+l15, cols gc0..gc0+3
#pragma unroll
    for (int mt = 0; mt < 4; ++mt) {
        const int gr = m0 + woffm + mt * 16 + l15;
#pragma unroll
        for (int nt = 0; nt < NTL; ++nt) {
            const int gc0 = n0 + woffn + nt * 16 + quad * 4;
            float v4[4];
#pragma unroll
            for (int rr = 0; rr < 4; ++rr) v4[rr] = acc[mt][nt][rr];
            if (HAS_BIAS) {
                const floatx4 bv = *(const floatx4*)(bias + gc0);
#pragma unroll
                for (int rr = 0; rr < 4; ++rr) v4[rr] += bv[rr];
            }
            if (MODE == 2 && gc0 >= 384) {
                const floatx4 bv = *(const floatx4*)(bias + gc0 - 384);
#pragma unroll
                for (int rr = 0; rr < 4; ++rr) v4[rr] += bv[rr];
            }
            if (MODE == 3 && gc0 >= 1536) {    // t2 region gets b_knn
                const floatx4 bv = *(const floatx4*)(bias + gc0 - 1536);
#pragma unroll
                for (int rr = 0; rr < 4; ++rr) v4[rr] += bv[rr];
            }
            if (ACT == 1) {
#pragma unroll
                for (int rr = 0; rr < 4; ++rr)
                    v4[rr] = 0.5f * v4[rr] * (1.0f + erff(v4[rr] * 0.70710678118654752f));
            }
            if (HAS_RES) {
                const floatx4 rv = *(const floatx4*)(res + (size_t)gr * ldc + gc0);
#pragma unroll
                for (int rr = 0; rr < 4; ++rr) v4[rr] += rv[rr];
            }
            if (MODE == 1 || (MODE == 3 && gc0 < 1152)) {
                const int t3  = gc0 / 384;
                const int rem = gc0 - t3 * 384;
                const int hh = rem >> 6, dd = rem & 63;
                const int bb = gr >> 10, nn = gr & 1023;
                u32 lo = cvt_pk_bf16(v4[0], v4[1]);
                u32 hi = cvt_pk_bf16(v4[2], v4[3]);
                *(uint2*)(Cb + ((size_t)((bb * 6 + hh) * 1024 + nn)) * 192 + t3 * 64 + dd) =
                    make_uint2(lo, hi);
            } else if (MODE == 3) {
                u32 lo = cvt_pk_bf16(v4[0], v4[1]);
                u32 hi = cvt_pk_bf16(v4[2], v4[3]);
                if (gc0 < 1536)
                    *(uint2*)(Cb2 + (size_t)gr * 384 + gc0 - 1152) = make_uint2(lo, hi);
                else
                    *(uint2*)(Cb3 + (size_t)gr * 384 + gc0 - 1536) = make_uint2(lo, hi);
            } else if (MODE == 2) {
                u32 lo = cvt_pk_bf16(v4[0], v4[1]);
                u32 hi = cvt_pk_bf16(v4[2], v4[3]);
                if (gc0 < 384)
                    *(uint2*)(Cb  + (size_t)gr * 384 + gc0)       = make_uint2(lo, hi);
                else
                    *(uint2*)(Cb2 + (size_t)gr * 384 + gc0 - 384) = make_uint2(lo, hi);
            } else if (OUT_F32) {
                floatx4 vv = {v4[0], v4[1], v4[2], v4[3]};
                *(floatx4*)(Cf + (size_t)gr * ldc + gc0) = vv;
            } else {
                u32 lo = cvt_pk_bf16(v4[0], v4[1]);
                u32 hi = cvt_pk_bf16(v4[2], v4[3]);
                *(uint2*)(Cb + (size_t)gr * ldc + gc0) = make_uint2(lo, hi);
            }
        }
    }
}

// ---------------- R20: proj GEMM + knnmax merged into one heterogeneous dispatch --------
// blocks [0, 768): proj = aout @ wprojT + bproj -> x1cat cols 0..383 (ld 768).
// blocks [768, 768+4096): knnmax, 4 rows/block (wave w -> row kb*4+w, lanes 0..47).
__global__ __launch_bounds__(256) void projknn_kernel(
    const u16* __restrict__ A,              // aout
    const u16* __restrict__ Bt,             // wprojT (384x384, ld 384)
    const float* __restrict__ bias,         // bproj
    const u16* __restrict__ t1,
    const u16* __restrict__ t2,
    const int* __restrict__ idx,
    u16* __restrict__ x1cat)
{
    constexpr int GB = 768;                 // GEMM blocks: (6 n) x (128 m)
    __shared__ u16 As[2][128 * 32];
    __shared__ u16 Bs[2][64 * 32];
    const int tid  = threadIdx.x;
    const int lane = tid & 63;

    if (blockIdx.x >= GB) {
        // ---------------- knnmax path ----------------
        const int bn = (blockIdx.x - GB) * 4 + (tid >> 6);
        if (lane >= 48) return;
        const int b = bn >> 10, n = bn & 1023;
        int ind[8];
#pragma unroll
        for (int k = 0; k < 8; ++k) ind[k] = idx[b * 8192 + k * 1024 + n];
        const int c0 = lane * 8;
        const size_t rbase = (size_t)bn * CDIM + c0;
        short8 v1 = *(const short8*)(t1 + rbase);
        short8 v2 = *(const short8*)(t2 + rbase);
        float basef[8], mx[8];
#pragma unroll
        for (int j = 0; j < 8; ++j) {
            basef[j] = b2f((u16)v2[j]) - b2f((u16)v1[j]);
            mx[j] = -1e30f;
        }
#pragma unroll
        for (int k = 0; k < 8; ++k) {
            short8 nv = *(const short8*)(t1 + (size_t)ind[k] * CDIM + c0);
#pragma unroll
            for (int j = 0; j < 8; ++j) {
                float v = b2f((u16)nv[j]) + basef[j];
                v = (v > 0.f) ? v : 0.2f * v;
                mx[j] = fmaxf(mx[j], v);
            }
        }
        short8 ov;
#pragma unroll
        for (int j = 0; j < 8; ++j) ov[j] = (short)f2b(mx[j]);
        *(short8*)(x1cat + (size_t)bn * 768 + CDIM + c0) = ov;
        return;
    }

    // ---------------- proj GEMM path (NT=64, MODE 0, bias, bf16 out ld 768) ----------
    const int wv   = tid >> 6;
    const int l15  = lane & 15;
    const int quad = lane >> 4;
    int lin = blockIdx.x;                   // [0, 768): chunked swizzle, cpx = 96
    lin = (lin & 7) * 96 + (lin >> 3);
    const int m0 = (lin / 6) * 128;
    const int n0 = (lin % 6) * 64;
    const int woffm = (wv >> 1) * 64;
    const int woffn = (wv & 1) * 32;

    floatx4 acc[4][2];
#pragma unroll
    for (int mt = 0; mt < 4; ++mt)
#pragma unroll
        for (int nt = 0; nt < 2; ++nt) acc[mt][nt] = (floatx4){0.f, 0.f, 0.f, 0.f};

    const int gsw  = 8 * ((lane & 3) ^ ((lane >> 3) & 3));
    const int rloc = lane >> 2;
    const int rdsw = 8 * (quad ^ ((l15 >> 1) & 3));

    auto stage = [&](int kt, int p) {
#pragma unroll
        for (int j = 0; j < 2; ++j) {
            const int slab = 32 * wv + 16 * j;
            gload_lds16(A + (size_t)(m0 + slab + rloc) * CDIM + kt + gsw, &As[p][slab * 32]);
        }
        const int slab = 16 * wv;
        gload_lds16(Bt + (size_t)(n0 + slab + rloc) * CDIM + kt + gsw, &Bs[p][slab * 32]);
    };

    stage(0, 0);
    stage(32, 1);
    int cur = 0;
    for (int kt = 0; kt < CDIM; kt += 32) {
        if (kt + 32 < CDIM) asm volatile("s_waitcnt vmcnt(3)" ::: "memory");
        else                asm volatile("s_waitcnt vmcnt(0)" ::: "memory");
        __builtin_amdgcn_sched_barrier(0);
        __builtin_amdgcn_s_barrier();
        __builtin_amdgcn_sched_barrier(0);

        short8 af[4], bf[2];
#pragma unroll
        for (int mt = 0; mt < 4; ++mt)
            af[mt] = *(const short8*)(As[cur] + (woffm + mt * 16 + l15) * 32 + rdsw);
#pragma unroll
        for (int nt = 0; nt < 2; ++nt)
            bf[nt] = *(const short8*)(Bs[cur] + (woffn + nt * 16 + l15) * 32 + rdsw);
#pragma unroll
        for (int mt = 0; mt < 4; ++mt)
#pragma unroll
            for (int nt = 0; nt < 2; ++nt)
                acc[mt][nt] = __builtin_amdgcn_mfma_f32_16x16x32_bf16(
                    bf[nt], af[mt], acc[mt][nt], 0, 0, 0);
        __builtin_amdgcn_sched_barrier(0);
        __builtin_amdgcn_s_barrier();
        __builtin_amdgcn_sched_barrier(0);
        if (kt + 64 < CDIM) stage(kt + 64, cur);
        cur ^= 1;
    }

#pragma unroll
    for (int mt = 0; mt < 4; ++mt) {
        const int gr = m0 + woffm + mt * 16 + l15;
#pragma unroll
        for (int nt = 0; nt < 2; ++nt) {
            const int gc0 = n0 + woffn + nt * 16 + quad * 4;
            const floatx4 bv = *(const floatx4*)(bias + gc0);
            float v4[4];
#pragma unroll
            for (int rr = 0; rr < 4; ++rr) v4[rr] = acc[mt][nt][rr] + bv[rr];
            u32 lo = cvt_pk_bf16(v4[0], v4[1]);
            u32 hi = cvt_pk_bf16(v4[2], v4[3]);
            *(uint2*)(x1cat + (size_t)gr * 768 + gc0) = make_uint2(lo, hi);
        }
    }
}

// ---------------- MFMA flash attention (R17: MFMA rowsum, T14 async-stage) --------------
__global__ __launch_bounds__(256) void attn_mfma_kernel(const u16* __restrict__ qkv2,
                                                        u16* __restrict__ aout)
{
    const int id = blockIdx.x;
    const int rxcd = id & 7;
    const int j = id >> 3;
    const int slab = rxcd + 8 * (j % 12);
    const int qtile = j / 12;
    const int b = slab / NH, h = slab % NH;

    const int wave = threadIdx.x >> 6;
    const int lane = threadIdx.x & 63;
    const int l15 = lane & 15;
    const int quad = lane >> 4;
    const int qbase = qtile * 128 + wave * 32;
    const int tid = threadIdx.x;

    const u16* slabp = qkv2 + ((size_t)(b * NH + h) << 10) * 192;

    __shared__ __align__(16) u16 Ks[64 * 72];
    __shared__ __align__(16) u16 Vt[64 * 72];
    __shared__ __align__(16) u16 Ps[4][32 * 72];

    short8 qf[2][2];
#pragma unroll
    for (int nt = 0; nt < 2; ++nt) {
        const u16* qrow = slabp + (size_t)(qbase + nt * 16 + l15) * 192;
        qf[nt][0] = *(const short8*)(qrow + quad * 8);
        qf[nt][1] = *(const short8*)(qrow + 32 + quad * 8);
    }

    short8 vones;
#pragma unroll
    for (int i = 0; i < 8; ++i) vones[i] = (l15 == 0) ? (short)0x3F80 : (short)0;

    floatx4 Oacc[2][4];
    floatx4 rAcc[2];
#pragma unroll
    for (int mt = 0; mt < 2; ++mt) {
        rAcc[mt] = (floatx4){0.f, 0.f, 0.f, 0.f};
#pragma unroll
        for (int nt = 0; nt < 4; ++nt) Oacc[mt][nt] = (floatx4){0.f, 0.f, 0.f, 0.f};
    }

    const int key = tid >> 2, dblk = (tid & 3) * 16;
    const int kp2 = tid & 31, db = (tid >> 5) * 8;
    uint4 kr0, kr1, vr0, vr1;
    {
        const u16* kp = slabp + (size_t)key * 192 + 64 + dblk;
        kr0 = *(const uint4*)(kp);
        kr1 = *(const uint4*)(kp + 8);
        const u16* vp = slabp + (size_t)(2 * kp2) * 192 + 128 + db;
        vr0 = *(const uint4*)(vp);
        vr1 = *(const uint4*)(vp + 192);
    }

    for (int kc = 0; kc < NNN; kc += 64) {
        *(uint4*)(Ks + key * 72 + dblk)     = kr0;
        *(uint4*)(Ks + key * 72 + dblk + 8) = kr1;
        {
            u32 a0[4] = {vr0.x, vr0.y, vr0.z, vr0.w};
            u32 a1[4] = {vr1.x, vr1.y, vr1.z, vr1.w};
#pragma unroll
            for (int i = 0; i < 4; ++i) {
                u32 lo = __builtin_amdgcn_perm(a1[i], a0[i], 0x05040100u);
                u32 hi = __builtin_amdgcn_perm(a1[i], a0[i], 0x07060302u);
                *(u32*)(Vt + (size_t)(db + 2 * i)     * 72 + 2 * kp2) = lo;
                *(u32*)(Vt + (size_t)(db + 2 * i + 1) * 72 + 2 * kp2) = hi;
            }
        }
        __syncthreads();

        if (kc + 64 < NNN) {
            const u16* kp = slabp + (size_t)(kc + 64 + key) * 192 + 64 + dblk;
            kr0 = *(const uint4*)(kp);
            kr1 = *(const uint4*)(kp + 8);
            const u16* vp = slabp + (size_t)(kc + 64 + 2 * kp2) * 192 + 128 + db;
            vr0 = *(const uint4*)(vp);
            vr1 = *(const uint4*)(vp + 192);
        }

        floatx4 sc[4][2];
        __builtin_amdgcn_s_setprio(1);
#pragma unroll
        for (int kt_ = 0; kt_ < 4; ++kt_) {
            short8 kf0 = *(const short8*)(Ks + (kt_ * 16 + l15) * 72 + quad * 8);
            short8 kf1 = *(const short8*)(Ks + (kt_ * 16 + l15) * 72 + 32 + quad * 8);
#pragma unroll
            for (int nt = 0; nt < 2; ++nt) {
                floatx4 s = {0.f, 0.f, 0.f, 0.f};
                s = __builtin_amdgcn_mfma_f32_16x16x32_bf16(kf0, qf[nt][0], s, 0, 0, 0);
                s = __builtin_amdgcn_mfma_f32_16x16x32_bf16(kf1, qf[nt][1], s, 0, 0, 0);
                sc[kt_][nt] = s;
            }
        }
        __builtin_amdgcn_s_setprio(0);

#pragma unroll
        for (int kt_ = 0; kt_ < 4; ++kt_)
#pragma unroll
            for (int nt = 0; nt < 2; ++nt) {
                float pv[4];
#pragma unroll
                for (int rr = 0; rr < 4; ++rr)
                    pv[rr] = __expf(sc[kt_][nt][rr] * 0.125f);
                u32 lo = cvt_pk_bf16(pv[0], pv[1]);
                u32 hi = cvt_pk_bf16(pv[2], pv[3]);
                *(uint2*)(Ps[wave] + (nt * 16 + l15) * 72 + kt_ * 16 + quad * 4) =
                    make_uint2(lo, hi);
            }

        short8 pf[2][2];
#pragma unroll
        for (int mt = 0; mt < 2; ++mt) {
            pf[mt][0] = *(const short8*)(Ps[wave] + (mt * 16 + l15) * 72 + quad * 8);
            pf[mt][1] = *(const short8*)(Ps[wave] + (mt * 16 + l15) * 72 + 32 + quad * 8);
        }
        __builtin_amdgcn_s_setprio(1);
#pragma unroll
        for (int mt = 0; mt < 2; ++mt) {
            rAcc[mt] = __builtin_amdgcn_mfma_f32_16x16x32_bf16(pf[mt][0], vones, rAcc[mt], 0, 0, 0);
            rAcc[mt] = __builtin_amdgcn_mfma_f32_16x16x32_bf16(pf[mt][1], vones, rAcc[mt], 0, 0, 0);
        }
#pragma unroll
        for (int nt = 0; nt < 4; ++nt) {
#pragma unroll
            for (int kk = 0; kk < 2; ++kk) {
                short8 vf = *(const short8*)(Vt + (size_t)(nt * 16 + l15) * 72 + kk * 32 + quad * 8);
#pragma unroll
                for (int mt = 0; mt < 2; ++mt)
                    Oacc[mt][nt] = __builtin_amdgcn_mfma_f32_16x16x32_bf16(
                        pf[mt][kk], vf, Oacc[mt][nt], 0, 0, 0);
            }
        }
        __builtin_amdgcn_s_setprio(0);
        __syncthreads();
    }

#pragma unroll
    for (int mt = 0; mt < 2; ++mt) {
#pragma unroll
        for (int rr = 0; rr < 4; ++rr) {
            float l = __shfl(rAcc[mt][rr], quad << 4, 64);
            float inv = 1.0f / l;
            int q = qbase + mt * 16 + quad * 4 + rr;
#pragma unroll
            for (int nt = 0; nt < 4; ++nt)
                aout[(size_t)(b * NNN + q) * CDIM + h * 64 + nt * 16 + l15] =
                    f2b(Oacc[mt][nt][rr] * inv);
        }
    }
}

extern "C" void kernel_launch(void* const* d_in, const int* in_sizes, int n_in,
                              void* d_out, int out_size, void* d_ws, size_t ws_size,
                              hipStream_t stream)
{
    (void)in_sizes; (void)n_in; (void)out_size; (void)ws_size;
    const float* x     = (const float*)d_in[0];
    const int*   knn   = (const int*)d_in[1];
    const float* ln1w  = (const float*)d_in[2];
    const float* ln1b  = (const float*)d_in[3];
    const float* wqkv  = (const float*)d_in[4];
    const float* wproj = (const float*)d_in[5];
    const float* bproj = (const float*)d_in[6];
    const float* wknn  = (const float*)d_in[7];
    const float* bknn  = (const float*)d_in[8];
    const float* wmrg  = (const float*)d_in[9];
    const float* bmrg  = (const float*)d_in[10];
    const float* ln2w  = (const float*)d_in[11];
    const float* ln2b  = (const float*)d_in[12];
    const float* wfc1  = (const float*)d_in[13];
    const float* bfc1  = (const float*)d_in[14];
    const float* wfc2  = (const float*)d_in[15];
    const float* bfc2  = (const float*)d_in[16];

    u16* wsb = (u16*)d_ws;
    const size_t RE = (size_t)BN_ROWS * CDIM;
    // buffer plan (stream-ordered reuse):
    u16* nxb   = wsb;                      // ln1 out; dead after FUSED
    u16* qkvb  = wsb + RE;                 // 3RE; dead after attn
    u16* aoutb = wsb;                      // attn out (over nx)
    u16* x1cat = wsb + RE;                 // projknn out (over qkv)
    u16* hinb  = wsb;                      // ln2 out (over aout)
    u16* h1b   = wsb + RE;                 // fc1 out (over x1cat)
    u16* t1b   = (u16*)d_out;              // FUSED out; dead after projknn
    u16* t2b   = (u16*)d_out + RE;         // FUSED out; dead after projknn
    float* xmid = (float*)d_out;           // merge out (over t1/t2); fc2 res + final out
    u16* wqkvT  = wsb + 4 * RE;            // 1152 x 384
    u16* wprojT = wqkvT + 442368;          // 384 x 384
    u16* wknnT  = wprojT + 147456;         // 384 x 768 (two K-halves)
    u16* wmrgT  = wknnT + 294912;          // 384 x 768
    u16* wfc1T  = wmrgT + 294912;          // 768 x 384
    u16* wfc2T  = wfc1T + 294912;          // 384 x 768

    // 0) pack all weights -> bf16 transposed (one launch)
    pack_all<<<dim3(36, 24, 6), 256, 0, stream>>>(
        wqkv, wqkvT, wproj, wprojT, wknn, wknnT, wmrg, wmrgT, wfc1, wfc1T, wfc2, wfc2T);
    // 1) nx = LN1(x)
    ln_kernel<<<BN_ROWS, 64, 0, stream>>>(x, ln1w, ln1b, nxb);
    // 2) FUSED qkv+knn: [qkv scatter | t1 | t2+b_knn], N=1920, grid (15,128)
    gemm_mfma_kernel<0, false, false, false, 3, 128, true><<<dim3(15, 128), 256, 0, stream>>>(
        nxb, CDIM, wqkvT, wknnT, 384, qkvb, t1b, t2b, nullptr, 0, bknn, nullptr, CDIM);
    // 3) attention -> aout (over nx)
    attn_mfma_kernel<<<768, 256, 0, stream>>>(qkvb, aoutb);
    // 4+5) proj GEMM + knnmax in ONE dispatch (independent; writes x1cat halves)
    projknn_kernel<<<768 + BN_ROWS / 4, 256, 0, stream>>>(
        aoutb, wprojT, bproj, t1b, t2b, knn, x1cat);
    // 6) xmid = x1cat @ w_merge + b_merge + x -> fp32 d_out (t1/t2 dead)
    gemm_mfma_kernel<0, true, true, true, 0, 64, true><<<dim3(6, 128), 256, 0, stream>>>(
        x1cat, 768, wmrgT, nullptr, 768, nullptr, nullptr, nullptr, xmid, CDIM, bmrg, x, 768);
    // 7) hin = LN2(xmid)
    ln_kernel<<<BN_ROWS, 64, 0, stream>>>(xmid, ln2w, ln2b, hinb);
    // 8) h1 = gelu(hin @ w_fc1 + b_fc1)
    gemm_mfma_kernel<1, true, false, false, 0, 128, true><<<dim3(6, 128), 256, 0, stream>>>(
        hinb, CDIM, wfc1T, nullptr, CDIM, h1b, nullptr, nullptr, nullptr, 768, bfc1, nullptr, CDIM);
    // 9) out = h1 @ w_fc2 + b_fc2 + xmid (in-place fp32 per-element)
    gemm_mfma_kernel<0, true, true, true, 0, 64, true><<<dim3(6, 128), 256, 0, stream>>>(
        h1b, 768, wfc2T, nullptr, 768, nullptr, nullptr, nullptr, (float*)d_out, CDIM, bfc2, xmid, 768);
}

// Round 15
// 292.714 us; speedup vs baseline: 1.0474x; 1.0133x over previous
//
#include <hip/hip_runtime.h>
#include <hip/hip_bf16.h>
#include <math.h>

// (B,N,C,H,K) = (16,1024,384,6,8), HID=768, HD=64
// R23 = R22 (296.2us confirmed best) + pack_all/ln1 merged into ONE heterogeneous
// dispatch (R11's proven mechanism, last unexploited instance): both independent,
// both precede the FUSED GEMM. Blocks [0,4096): LN1 4 rows/block (1 row/wave);
// blocks [4096,9280): the 5184 pack tiles (linear->3D decode).
#define BN_ROWS 16384
#define CDIM 384
#define NH 6
#define BBATCH 16
#define NNN 1024

typedef unsigned short u16;
typedef unsigned int u32;
typedef __attribute__((ext_vector_type(8))) short short8;
typedef __attribute__((ext_vector_type(4))) float floatx4;

__device__ __forceinline__ float b2f(u16 s) { return __uint_as_float(((u32)s) << 16); }
__device__ __forceinline__ u16 f2b(float f) {
    __hip_bfloat16 h = __float2bfloat16(f);
    u16 s; __builtin_memcpy(&s, &h, 2); return s;
}
// packed bf16 convert (RNE, same as __float2bfloat16): lo -> low16, hi -> high16
__device__ __forceinline__ u32 cvt_pk_bf16(float lo, float hi) {
    u32 r;
    asm("v_cvt_pk_bf16_f32 %0, %1, %2" : "=v"(r) : "v"(lo), "v"(hi));
    return r;
}
__device__ __forceinline__ void gload_lds16(const u16* g, u16* l) {
    __builtin_amdgcn_global_load_lds(
        (const __attribute__((address_space(1))) unsigned int*)g,
        (__attribute__((address_space(3))) unsigned int*)l, 16, 0, 0);
}

// ---------------- R23: fused [LN1 | weight-pack] heterogeneous dispatch ----------------
// blocks [0, 4096): LN1 of rows blockIdx*4 + wave (fp32 in, bf16 out).
// blocks [4096, 9280): pack tile t = blockIdx-4096: W (KxN fp32) -> Wt (NxK bf16);
//   z = t/864 selects weight, rem = t%864: by = rem/36, bx = rem%36.
__global__ __launch_bounds__(256) void packln_kernel(
    const float* __restrict__ xin, const float* __restrict__ lnw,
    const float* __restrict__ lnb, u16* __restrict__ lnout,
    const float* __restrict__ W0, u16* __restrict__ T0,
    const float* __restrict__ W1, u16* __restrict__ T1,
    const float* __restrict__ W2, u16* __restrict__ T2,
    const float* __restrict__ W3, u16* __restrict__ T3,
    const float* __restrict__ W4, u16* __restrict__ T4,
    const float* __restrict__ W5, u16* __restrict__ T5)
{
    const int tid = threadIdx.x;
    if (blockIdx.x < 4096) {
        // ---------------- LN1 path: wave w -> row blockIdx*4 + w ----------------
        const int row = blockIdx.x * 4 + (tid >> 6);
        const int t = tid & 63;
        const size_t base = (size_t)row * CDIM;
        float v[6];
#pragma unroll
        for (int i = 0; i < 6; ++i) v[i] = xin[base + t + 64 * i];
        float s = 0.f, s2 = 0.f;
#pragma unroll
        for (int i = 0; i < 6; ++i) { s += v[i]; s2 += v[i] * v[i]; }
#pragma unroll
        for (int m = 1; m < 64; m <<= 1) {
            s  += __shfl_xor(s,  m, 64);
            s2 += __shfl_xor(s2, m, 64);
        }
        const float mean = s * (1.0f / CDIM);
        const float var  = s2 * (1.0f / CDIM) - mean * mean;
        const float rs   = rsqrtf(var + 1e-5f);
#pragma unroll
        for (int i = 0; i < 6; ++i) {
            int c = t + 64 * i;
            lnout[base + c] = f2b((v[i] - mean) * rs * lnw[c] + lnb[c]);
        }
        return;
    }

    // ---------------- pack path ----------------
    const int tix = blockIdx.x - 4096;
    const int bz = tix / 864;
    const int rem = tix - bz * 864;
    const int by = rem / 36, bx = rem - (rem / 36) * 36;
    const float* W; u16* T; int K, N;
    switch (bz) {
        case 0: W = W0; T = T0; K = 384; N = 1152; break;
        case 1: W = W1; T = T1; K = 384; N = 384;  break;
        case 2: W = W2; T = T2; K = 768; N = 384;  break;
        case 3: W = W3; T = T3; K = 768; N = 384;  break;
        case 4: W = W4; T = T4; K = 384; N = 768;  break;
        default: W = W5; T = T5; K = 768; N = 384; break;
    }
    const int n0 = bx * 32, k0 = by * 32;
    if (n0 >= N || k0 >= K) return;
    __shared__ float s[32][33];
    const int tx = tid & 31, ty = tid >> 5;
#pragma unroll
    for (int i = 0; i < 4; ++i)
        s[ty + 8 * i][tx] = W[(size_t)(k0 + ty + 8 * i) * N + n0 + tx];
    __syncthreads();
#pragma unroll
    for (int i = 0; i < 4; ++i)
        T[(size_t)(n0 + ty + 8 * i) * K + k0 + tx] = f2b(s[tx][ty + 8 * i]);
}

// ---------------- LayerNorm: one wave per row; fp32 in, bf16 out (ln2) ----------------
__global__ __launch_bounds__(64) void ln_kernel(const float* __restrict__ xin,
                                                const float* __restrict__ w,
                                                const float* __restrict__ b,
                                                u16* __restrict__ out)
{
    const int row = blockIdx.x;
    const int t = threadIdx.x;
    const size_t base = (size_t)row * CDIM;
    float v[6];
#pragma unroll
    for (int i = 0; i < 6; ++i) v[i] = xin[base + t + 64 * i];
    float s = 0.f, s2 = 0.f;
#pragma unroll
    for (int i = 0; i < 6; ++i) { s += v[i]; s2 += v[i] * v[i]; }
#pragma unroll
    for (int m = 1; m < 64; m <<= 1) {
        s  += __shfl_xor(s,  m, 64);
        s2 += __shfl_xor(s2, m, 64);
    }
    const float mean = s * (1.0f / CDIM);
    const float var  = s2 * (1.0f / CDIM) - mean * mean;
    const float rs   = rsqrtf(var + 1e-5f);
#pragma unroll
    for (int i = 0; i < 6; ++i) {
        int c = t + 64 * i;
        out[base + c] = f2b((v[i] - mean) * rs * w[c] + b[c]);
    }
}

// ---------------- MFMA GEMM, 2-buffer counted-vmcnt (R18), transposed-C -----------------
// A (MxK bf16) @ Bt^T (Bt is NxK bf16). 128xNT tile, BK=32, 4 waves.
// R10: chunked XCD swizzle. R12: transposed-C epilogue. R13/14: counted-vmcnt 2-deep
// pipeline, raw barriers (proven race-free). 2-buffer LDS: NT=128 -> 32KB.
// MODE: 0 normal, 1 qkv head-blocked scatter, 2 split t1/t2,
//       3 FUSED qkv+knn: n-regions [0,1152) qkv-scatter | [1152,1536) t1 |
//         [1536,1920) t2+b_knn.
template<int ACT, bool HAS_BIAS, bool HAS_RES, bool OUT_F32, int MODE, int NT, bool SWZ>
__global__ __launch_bounds__(256) void gemm_mfma_kernel(
    const u16* __restrict__ A, int lda,
    const u16* __restrict__ Bt, const u16* __restrict__ Bt2, int ldbt,
    u16* Cb, u16* Cb2, u16* Cb3, float* Cf, int ldc,
    const float* __restrict__ bias,
    const float* res,
    int K)
{
    constexpr int NTL = NT / 32;           // n-tiles per wave
    __shared__ u16 As[2][128 * 32];
    __shared__ u16 Bs[2][NT * 32];
    const int tid  = threadIdx.x;
    const int wv   = tid >> 6;
    const int lane = tid & 63;
    const int l15  = lane & 15;
    const int quad = lane >> 4;

    int m0, n0;
    if (SWZ) {
        const int nbx = gridDim.x;
        const int total = nbx * gridDim.y;
        int lin = blockIdx.x + nbx * blockIdx.y;
        const int cpx = total >> 3;
        lin = (lin & 7) * cpx + (lin >> 3);
        m0 = (lin / nbx) * 128;
        n0 = (lin % nbx) * NT;
    } else {
        m0 = blockIdx.y * 128;
        n0 = blockIdx.x * NT;
    }

    const int woffm = (wv >> 1) * 64;
    const int woffn = (wv & 1) * (NT / 2);

    // B-source routing (block-uniform)
    const u16* bsrc; int brow0, koff, bld;
    if constexpr (MODE == 3) {
        if (n0 < 1152)      { bsrc = Bt;  brow0 = n0;        koff = 0;   bld = 384; }
        else if (n0 < 1536) { bsrc = Bt2; brow0 = n0 - 1152; koff = 0;   bld = 768; }
        else                { bsrc = Bt2; brow0 = n0 - 1536; koff = 384; bld = 768; }
    } else {
        bsrc  = (MODE == 2 && n0 >= 384) ? Bt2 : Bt;
        brow0 = (MODE == 2 && n0 >= 384) ? (n0 - 384) : n0;
        koff = 0; bld = ldbt;
    }

    floatx4 acc[4][NTL];
#pragma unroll
    for (int mt = 0; mt < 4; ++mt)
#pragma unroll
        for (int nt = 0; nt < NTL; ++nt) acc[mt][nt] = (floatx4){0.f, 0.f, 0.f, 0.f};

    const int gsw  = 8 * ((lane & 3) ^ ((lane >> 3) & 3));  // fetch-granule swizzle
    const int rloc = lane >> 2;                              // row within 16-row slab
    const int rdsw = 8 * (quad ^ ((l15 >> 1) & 3));          // read-granule swizzle

    auto stage = [&](int kt, int p) {
#pragma unroll
        for (int j = 0; j < 2; ++j) {
            const int slab = 32 * wv + 16 * j;
            gload_lds16(A + (size_t)(m0 + slab + rloc) * lda + kt + gsw, &As[p][slab * 32]);
        }
        if (NT == 128) {
#pragma unroll
            for (int j = 0; j < 2; ++j) {
                const int slab = 32 * wv + 16 * j;
                gload_lds16(bsrc + (size_t)(brow0 + slab + rloc) * bld + koff + kt + gsw,
                            &Bs[p][slab * 32]);
            }
        } else {
            const int slab = 16 * wv;
            gload_lds16(bsrc + (size_t)(brow0 + slab + rloc) * bld + koff + kt + gsw,
                        &Bs[p][slab * 32]);
        }
    };

    stage(0, 0);
    stage(32, 1);
    int cur = 0;
    for (int kt = 0; kt < K; kt += 32) {
        if (kt + 32 < K) {
            if constexpr (NT == 128) asm volatile("s_waitcnt vmcnt(4)" ::: "memory");
            else                     asm volatile("s_waitcnt vmcnt(3)" ::: "memory");
        } else {
            asm volatile("s_waitcnt vmcnt(0)" ::: "memory");
        }
        __builtin_amdgcn_sched_barrier(0);
        __builtin_amdgcn_s_barrier();          // buf[cur] visible to all waves
        __builtin_amdgcn_sched_barrier(0);

        short8 af[4], bf[NTL];
#pragma unroll
        for (int mt = 0; mt < 4; ++mt)
            af[mt] = *(const short8*)(As[cur] + (woffm + mt * 16 + l15) * 32 + rdsw);
#pragma unroll
        for (int nt = 0; nt < NTL; ++nt)
            bf[nt] = *(const short8*)(Bs[cur] + (woffn + nt * 16 + l15) * 32 + rdsw);
#pragma unroll
        for (int mt = 0; mt < 4; ++mt)
#pragma unroll
            for (int nt = 0; nt < NTL; ++nt)
                acc[mt][nt] = __builtin_amdgcn_mfma_f32_16x16x32_bf16(
                    bf[nt], af[mt], acc[mt][nt], 0, 0, 0);
        __builtin_amdgcn_sched_barrier(0);
        __builtin_amdgcn_s_barrier();          // all waves done reading buf[cur]
        __builtin_amdgcn_sched_barrier(0);
        if (kt + 64 < K) stage(kt + 64, cur);  // async refill; waited 2 iters later
        cur ^= 1;
    }

    // epilogue (transposed-C): lane holds rows gr = ..+l15, cols gc0..gc0+3
#pragma unroll
    for (int mt = 0; mt < 4; ++mt) {
        const int gr = m0 + woffm + mt * 16 + l15;
#pragma unroll
        for (int nt = 0; nt < NTL; ++nt) {
            const int gc0 = n0 + woffn + nt * 16 + quad * 4;
            float v4[4];
#pragma unroll
            for (int rr = 0; rr < 4; ++rr) v4[rr] = acc[mt][nt][rr];
            if (HAS_BIAS) {
                const floatx4 bv = *(const floatx4*)(bias + gc0);
#pragma unroll
                for (int rr = 0; rr < 4; ++rr) v4[rr] += bv[rr];
            }
            if (MODE == 2 && gc0 >= 384) {
                const floatx4 bv = *(const floatx4*)(bias + gc0 - 384);
#pragma unroll
                for (int rr = 0; rr < 4; ++rr) v4[rr] += bv[rr];
            }
            if (MODE == 3 && gc0 >= 1536) {    // t2 region gets b_knn
                const floatx4 bv = *(const floatx4*)(bias + gc0 - 1536);
#pragma unroll
                for (int rr = 0; rr < 4; ++rr) v4[rr] += bv[rr];
            }
            if (ACT == 1) {
#pragma unroll
                for (int rr = 0; rr < 4; ++rr)
                    v4[rr] = 0.5f * v4[rr] * (1.0f + erff(v4[rr] * 0.70710678118654752f));
            }
            if (HAS_RES) {
                const floatx4 rv = *(const floatx4*)(res + (size_t)gr * ldc + gc0);
#pragma unroll
                for (int rr = 0; rr < 4; ++rr) v4[rr] += rv[rr];
            }
            if (MODE == 1 || (MODE == 3 && gc0 < 1152)) {
                const int t3  = gc0 / 384;
                const int rem = gc0 - t3 * 384;
                const int hh = rem >> 6, dd = rem & 63;
                const int bb = gr >> 10, nn = gr & 1023;
                u32 lo = cvt_pk_bf16(v4[0], v4[1]);
                u32 hi = cvt_pk_bf16(v4[2], v4[3]);
                *(uint2*)(Cb + ((size_t)((bb * 6 + hh) * 1024 + nn)) * 192 + t3 * 64 + dd) =
                    make_uint2(lo, hi);
            } else if (MODE == 3) {
                u32 lo = cvt_pk_bf16(v4[0], v4[1]);
                u32 hi = cvt_pk_bf16(v4[2], v4[3]);
                if (gc0 < 1536)
                    *(uint2*)(Cb2 + (size_t)gr * 384 + gc0 - 1152) = make_uint2(lo, hi);
                else
                    *(uint2*)(Cb3 + (size_t)gr * 384 + gc0 - 1536) = make_uint2(lo, hi);
            } else if (MODE == 2) {
                u32 lo = cvt_pk_bf16(v4[0], v4[1]);
                u32 hi = cvt_pk_bf16(v4[2], v4[3]);
                if (gc0 < 384)
                    *(uint2*)(Cb  + (size_t)gr * 384 + gc0)       = make_uint2(lo, hi);
                else
                    *(uint2*)(Cb2 + (size_t)gr * 384 + gc0 - 384) = make_uint2(lo, hi);
            } else if (OUT_F32) {
                floatx4 vv = {v4[0], v4[1], v4[2], v4[3]};
                *(floatx4*)(Cf + (size_t)gr * ldc + gc0) = vv;
            } else {
                u32 lo = cvt_pk_bf16(v4[0], v4[1]);
                u32 hi = cvt_pk_bf16(v4[2], v4[3]);
                *(uint2*)(Cb + (size_t)gr * ldc + gc0) = make_uint2(lo, hi);
            }
        }
    }
}

// ---------------- R20: proj GEMM + knnmax merged into one heterogeneous dispatch --------
// blocks [0, 768): proj = aout @ wprojT + bproj -> x1cat cols 0..383 (ld 768).
// blocks [768, 768+4096): knnmax, 4 rows/block (wave w -> row kb*4+w, lanes 0..47).
__global__ __launch_bounds__(256) void projknn_kernel(
    const u16* __restrict__ A,              // aout
    const u16* __restrict__ Bt,             // wprojT (384x384, ld 384)
    const float* __restrict__ bias,         // bproj
    const u16* __restrict__ t1,
    const u16* __restrict__ t2,
    const int* __restrict__ idx,
    u16* __restrict__ x1cat)
{
    constexpr int GB = 768;                 // GEMM blocks: (6 n) x (128 m)
    __shared__ u16 As[2][128 * 32];
    __shared__ u16 Bs[2][64 * 32];
    const int tid  = threadIdx.x;
    const int lane = tid & 63;

    if (blockIdx.x >= GB) {
        // ---------------- knnmax path ----------------
        const int bn = (blockIdx.x - GB) * 4 + (tid >> 6);
        if (lane >= 48) return;
        const int b = bn >> 10, n = bn & 1023;
        int ind[8];
#pragma unroll
        for (int k = 0; k < 8; ++k) ind[k] = idx[b * 8192 + k * 1024 + n];
        const int c0 = lane * 8;
        const size_t rbase = (size_t)bn * CDIM + c0;
        short8 v1 = *(const short8*)(t1 + rbase);
        short8 v2 = *(const short8*)(t2 + rbase);
        float basef[8], mx[8];
#pragma unroll
        for (int j = 0; j < 8; ++j) {
            basef[j] = b2f((u16)v2[j]) - b2f((u16)v1[j]);
            mx[j] = -1e30f;
        }
#pragma unroll
        for (int k = 0; k < 8; ++k) {
            short8 nv = *(const short8*)(t1 + (size_t)ind[k] * CDIM + c0);
#pragma unroll
            for (int j = 0; j < 8; ++j) {
                float v = b2f((u16)nv[j]) + basef[j];
                v = (v > 0.f) ? v : 0.2f * v;
                mx[j] = fmaxf(mx[j], v);
            }
        }
        short8 ov;
#pragma unroll
        for (int j = 0; j < 8; ++j) ov[j] = (short)f2b(mx[j]);
        *(short8*)(x1cat + (size_t)bn * 768 + CDIM + c0) = ov;
        return;
    }

    // ---------------- proj GEMM path (NT=64, MODE 0, bias, bf16 out ld 768) ----------
    const int wv   = tid >> 6;
    const int l15  = lane & 15;
    const int quad = lane >> 4;
    int lin = blockIdx.x;                   // [0, 768): chunked swizzle, cpx = 96
    lin = (lin & 7) * 96 + (lin >> 3);
    const int m0 = (lin / 6) * 128;
    const int n0 = (lin % 6) * 64;
    const int woffm = (wv >> 1) * 64;
    const int woffn = (wv & 1) * 32;

    floatx4 acc[4][2];
#pragma unroll
    for (int mt = 0; mt < 4; ++mt)
#pragma unroll
        for (int nt = 0; nt < 2; ++nt) acc[mt][nt] = (floatx4){0.f, 0.f, 0.f, 0.f};

    const int gsw  = 8 * ((lane & 3) ^ ((lane >> 3) & 3));
    const int rloc = lane >> 2;
    const int rdsw = 8 * (quad ^ ((l15 >> 1) & 3));

    auto stage = [&](int kt, int p) {
#pragma unroll
        for (int j = 0; j < 2; ++j) {
            const int slab = 32 * wv + 16 * j;
            gload_lds16(A + (size_t)(m0 + slab + rloc) * CDIM + kt + gsw, &As[p][slab * 32]);
        }
        const int slab = 16 * wv;
        gload_lds16(Bt + (size_t)(n0 + slab + rloc) * CDIM + kt + gsw, &Bs[p][slab * 32]);
    };

    stage(0, 0);
    stage(32, 1);
    int cur = 0;
    for (int kt = 0; kt < CDIM; kt += 32) {
        if (kt + 32 < CDIM) asm volatile("s_waitcnt vmcnt(3)" ::: "memory");
        else                asm volatile("s_waitcnt vmcnt(0)" ::: "memory");
        __builtin_amdgcn_sched_barrier(0);
        __builtin_amdgcn_s_barrier();
        __builtin_amdgcn_sched_barrier(0);

        short8 af[4], bf[2];
#pragma unroll
        for (int mt = 0; mt < 4; ++mt)
            af[mt] = *(const short8*)(As[cur] + (woffm + mt * 16 + l15) * 32 + rdsw);
#pragma unroll
        for (int nt = 0; nt < 2; ++nt)
            bf[nt] = *(const short8*)(Bs[cur] + (woffn + nt * 16 + l15) * 32 + rdsw);
#pragma unroll
        for (int mt = 0; mt < 4; ++mt)
#pragma unroll
            for (int nt = 0; nt < 2; ++nt)
                acc[mt][nt] = __builtin_amdgcn_mfma_f32_16x16x32_bf16(
                    bf[nt], af[mt], acc[mt][nt], 0, 0, 0);
        __builtin_amdgcn_sched_barrier(0);
        __builtin_amdgcn_s_barrier();
        __builtin_amdgcn_sched_barrier(0);
        if (kt + 64 < CDIM) stage(kt + 64, cur);
        cur ^= 1;
    }

#pragma unroll
    for (int mt = 0; mt < 4; ++mt) {
        const int gr = m0 + woffm + mt * 16 + l15;
#pragma unroll
        for (int nt = 0; nt < 2; ++nt) {
            const int gc0 = n0 + woffn + nt * 16 + quad * 4;
            const floatx4 bv = *(const floatx4*)(bias + gc0);
            float v4[4];
#pragma unroll
            for (int rr = 0; rr < 4; ++rr) v4[rr] = acc[mt][nt][rr] + bv[rr];
            u32 lo = cvt_pk_bf16(v4[0], v4[1]);
            u32 hi = cvt_pk_bf16(v4[2], v4[3]);
            *(uint2*)(x1cat + (size_t)gr * 768 + gc0) = make_uint2(lo, hi);
        }
    }
}

// ---------------- MFMA flash attention (R17: MFMA rowsum, T14 async-stage) --------------
__global__ __launch_bounds__(256) void attn_mfma_kernel(const u16* __restrict__ qkv2,
                                                        u16* __restrict__ aout)
{
    const int id = blockIdx.x;
    const int rxcd = id & 7;
    const int j = id >> 3;
    const int slab = rxcd + 8 * (j % 12);
    const int qtile = j / 12;
    const int b = slab / NH, h = slab % NH;

    const int wave = threadIdx.x >> 6;
    const int lane = threadIdx.x & 63;
    const int l15 = lane & 15;
    const int quad = lane >> 4;
    const int qbase = qtile * 128 + wave * 32;
    const int tid = threadIdx.x;

    const u16* slabp = qkv2 + ((size_t)(b * NH + h) << 10) * 192;

    __shared__ __align__(16) u16 Ks[64 * 72];
    __shared__ __align__(16) u16 Vt[64 * 72];
    __shared__ __align__(16) u16 Ps[4][32 * 72];

    short8 qf[2][2];
#pragma unroll
    for (int nt = 0; nt < 2; ++nt) {
        const u16* qrow = slabp + (size_t)(qbase + nt * 16 + l15) * 192;
        qf[nt][0] = *(const short8*)(qrow + quad * 8);
        qf[nt][1] = *(const short8*)(qrow + 32 + quad * 8);
    }

    short8 vones;
#pragma unroll
    for (int i = 0; i < 8; ++i) vones[i] = (l15 == 0) ? (short)0x3F80 : (short)0;

    floatx4 Oacc[2][4];
    floatx4 rAcc[2];
#pragma unroll
    for (int mt = 0; mt < 2; ++mt) {
        rAcc[mt] = (floatx4){0.f, 0.f, 0.f, 0.f};
#pragma unroll
        for (int nt = 0; nt < 4; ++nt) Oacc[mt][nt] = (floatx4){0.f, 0.f, 0.f, 0.f};
    }

    const int key = tid >> 2, dblk = (tid & 3) * 16;
    const int kp2 = tid & 31, db = (tid >> 5) * 8;
    uint4 kr0, kr1, vr0, vr1;
    {
        const u16* kp = slabp + (size_t)key * 192 + 64 + dblk;
        kr0 = *(const uint4*)(kp);
        kr1 = *(const uint4*)(kp + 8);
        const u16* vp = slabp + (size_t)(2 * kp2) * 192 + 128 + db;
        vr0 = *(const uint4*)(vp);
        vr1 = *(const uint4*)(vp + 192);
    }

    for (int kc = 0; kc < NNN; kc += 64) {
        *(uint4*)(Ks + key * 72 + dblk)     = kr0;
        *(uint4*)(Ks + key * 72 + dblk + 8) = kr1;
        {
            u32 a0[4] = {vr0.x, vr0.y, vr0.z, vr0.w};
            u32 a1[4] = {vr1.x, vr1.y, vr1.z, vr1.w};
#pragma unroll
            for (int i = 0; i < 4; ++i) {
                u32 lo = __builtin_amdgcn_perm(a1[i], a0[i], 0x05040100u);
                u32 hi = __builtin_amdgcn_perm(a1[i], a0[i], 0x07060302u);
                *(u32*)(Vt + (size_t)(db + 2 * i)     * 72 + 2 * kp2) = lo;
                *(u32*)(Vt + (size_t)(db + 2 * i + 1) * 72 + 2 * kp2) = hi;
            }
        }
        __syncthreads();

        if (kc + 64 < NNN) {
            const u16* kp = slabp + (size_t)(kc + 64 + key) * 192 + 64 + dblk;
            kr0 = *(const uint4*)(kp);
            kr1 = *(const uint4*)(kp + 8);
            const u16* vp = slabp + (size_t)(kc + 64 + 2 * kp2) * 192 + 128 + db;
            vr0 = *(const uint4*)(vp);
            vr1 = *(const uint4*)(vp + 192);
        }

        floatx4 sc[4][2];
        __builtin_amdgcn_s_setprio(1);
#pragma unroll
        for (int kt_ = 0; kt_ < 4; ++kt_) {
            short8 kf0 = *(const short8*)(Ks + (kt_ * 16 + l15) * 72 + quad * 8);
            short8 kf1 = *(const short8*)(Ks + (kt_ * 16 + l15) * 72 + 32 + quad * 8);
#pragma unroll
            for (int nt = 0; nt < 2; ++nt) {
                floatx4 s = {0.f, 0.f, 0.f, 0.f};
                s = __builtin_amdgcn_mfma_f32_16x16x32_bf16(kf0, qf[nt][0], s, 0, 0, 0);
                s = __builtin_amdgcn_mfma_f32_16x16x32_bf16(kf1, qf[nt][1], s, 0, 0, 0);
                sc[kt_][nt] = s;
            }
        }
        __builtin_amdgcn_s_setprio(0);

#pragma unroll
        for (int kt_ = 0; kt_ < 4; ++kt_)
#pragma unroll
            for (int nt = 0; nt < 2; ++nt) {
                float pv[4];
#pragma unroll
                for (int rr = 0; rr < 4; ++rr)
                    pv[rr] = __expf(sc[kt_][nt][rr] * 0.125f);
                u32 lo = cvt_pk_bf16(pv[0], pv[1]);
                u32 hi = cvt_pk_bf16(pv[2], pv[3]);
                *(uint2*)(Ps[wave] + (nt * 16 + l15) * 72 + kt_ * 16 + quad * 4) =
                    make_uint2(lo, hi);
            }

        short8 pf[2][2];
#pragma unroll
        for (int mt = 0; mt < 2; ++mt) {
            pf[mt][0] = *(const short8*)(Ps[wave] + (mt * 16 + l15) * 72 + quad * 8);
            pf[mt][1] = *(const short8*)(Ps[wave] + (mt * 16 + l15) * 72 + 32 + quad * 8);
        }
        __builtin_amdgcn_s_setprio(1);
#pragma unroll
        for (int mt = 0; mt < 2; ++mt) {
            rAcc[mt] = __builtin_amdgcn_mfma_f32_16x16x32_bf16(pf[mt][0], vones, rAcc[mt], 0, 0, 0);
            rAcc[mt] = __builtin_amdgcn_mfma_f32_16x16x32_bf16(pf[mt][1], vones, rAcc[mt], 0, 0, 0);
        }
#pragma unroll
        for (int nt = 0; nt < 4; ++nt) {
#pragma unroll
            for (int kk = 0; kk < 2; ++kk) {
                short8 vf = *(const short8*)(Vt + (size_t)(nt * 16 + l15) * 72 + kk * 32 + quad * 8);
#pragma unroll
                for (int mt = 0; mt < 2; ++mt)
                    Oacc[mt][nt] = __builtin_amdgcn_mfma_f32_16x16x32_bf16(
                        pf[mt][kk], vf, Oacc[mt][nt], 0, 0, 0);
            }
        }
        __builtin_amdgcn_s_setprio(0);
        __syncthreads();
    }

#pragma unroll
    for (int mt = 0; mt < 2; ++mt) {
#pragma unroll
        for (int rr = 0; rr < 4; ++rr) {
            float l = __shfl(rAcc[mt][rr], quad << 4, 64);
            float inv = 1.0f / l;
            int q = qbase + mt * 16 + quad * 4 + rr;
#pragma unroll
            for (int nt = 0; nt < 4; ++nt)
                aout[(size_t)(b * NNN + q) * CDIM + h * 64 + nt * 16 + l15] =
                    f2b(Oacc[mt][nt][rr] * inv);
        }
    }
}

extern "C" void kernel_launch(void* const* d_in, const int* in_sizes, int n_in,
                              void* d_out, int out_size, void* d_ws, size_t ws_size,
                              hipStream_t stream)
{
    (void)in_sizes; (void)n_in; (void)out_size; (void)ws_size;
    const float* x     = (const float*)d_in[0];
    const int*   knn   = (const int*)d_in[1];
    const float* ln1w  = (const float*)d_in[2];
    const float* ln1b  = (const float*)d_in[3];
    const float* wqkv  = (const float*)d_in[4];
    const float* wproj = (const float*)d_in[5];
    const float* bproj = (const float*)d_in[6];
    const float* wknn  = (const float*)d_in[7];
    const float* bknn  = (const float*)d_in[8];
    const float* wmrg  = (const float*)d_in[9];
    const float* bmrg  = (const float*)d_in[10];
    const float* ln2w  = (const float*)d_in[11];
    const float* ln2b  = (const float*)d_in[12];
    const float* wfc1  = (const float*)d_in[13];
    const float* bfc1  = (const float*)d_in[14];
    const float* wfc2  = (const float*)d_in[15];
    const float* bfc2  = (const float*)d_in[16];

    u16* wsb = (u16*)d_ws;
    const size_t RE = (size_t)BN_ROWS * CDIM;
    // buffer plan (stream-ordered reuse):
    u16* nxb   = wsb;                      // ln1 out; dead after FUSED
    u16* qkvb  = wsb + RE;                 // 3RE; dead after attn
    u16* aoutb = wsb;                      // attn out (over nx)
    u16* x1cat = wsb + RE;                 // projknn out (over qkv)
    u16* hinb  = wsb;                      // ln2 out (over aout)
    u16* h1b   = wsb + RE;                 // fc1 out (over x1cat)
    u16* t1b   = (u16*)d_out;              // FUSED out; dead after projknn
    u16* t2b   = (u16*)d_out + RE;         // FUSED out; dead after projknn
    float* xmid = (float*)d_out;           // merge out (over t1/t2); fc2 res + final out
    u16* wqkvT  = wsb + 4 * RE;            // 1152 x 384
    u16* wprojT = wqkvT + 442368;          // 384 x 384
    u16* wknnT  = wprojT + 147456;         // 384 x 768 (two K-halves)
    u16* wmrgT  = wknnT + 294912;          // 384 x 768
    u16* wfc1T  = wmrgT + 294912;          // 768 x 384
    u16* wfc2T  = wfc1T + 294912;          // 384 x 768

    // 0+1) pack all weights + LN1 in ONE heterogeneous dispatch (independent)
    packln_kernel<<<4096 + 5184, 256, 0, stream>>>(
        x, ln1w, ln1b, nxb,
        wqkv, wqkvT, wproj, wprojT, wknn, wknnT, wmrg, wmrgT, wfc1, wfc1T, wfc2, wfc2T);
    // 2) FUSED qkv+knn: [qkv scatter | t1 | t2+b_knn], N=1920, grid (15,128)
    gemm_mfma_kernel<0, false, false, false, 3, 128, true><<<dim3(15, 128), 256, 0, stream>>>(
        nxb, CDIM, wqkvT, wknnT, 384, qkvb, t1b, t2b, nullptr, 0, bknn, nullptr, CDIM);
    // 3) attention -> aout (over nx)
    attn_mfma_kernel<<<768, 256, 0, stream>>>(qkvb, aoutb);
    // 4+5) proj GEMM + knnmax in ONE dispatch (independent; writes x1cat halves)
    projknn_kernel<<<768 + BN_ROWS / 4, 256, 0, stream>>>(
        aoutb, wprojT, bproj, t1b, t2b, knn, x1cat);
    // 6) xmid = x1cat @ w_merge + b_merge + x -> fp32 d_out (t1/t2 dead)
    gemm_mfma_kernel<0, true, true, true, 0, 64, true><<<dim3(6, 128), 256, 0, stream>>>(
        x1cat, 768, wmrgT, nullptr, 768, nullptr, nullptr, nullptr, xmid, CDIM, bmrg, x, 768);
    // 7) hin = LN2(xmid)
    ln_kernel<<<BN_ROWS, 64, 0, stream>>>(xmid, ln2w, ln2b, hinb);
    // 8) h1 = gelu(hin @ w_fc1 + b_fc1)
    gemm_mfma_kernel<1, true, false, false, 0, 128, true><<<dim3(6, 128), 256, 0, stream>>>(
        hinb, CDIM, wfc1T, nullptr, CDIM, h1b, nullptr, nullptr, nullptr, 768, bfc1, nullptr, CDIM);
    // 9) out = h1 @ w_fc2 + b_fc2 + xmid (in-place fp32 per-element)
    gemm_mfma_kernel<0, true, true, true, 0, 64, true><<<dim3(6, 128), 256, 0, stream>>>(
        h1b, 768, wfc2T, nullptr, 768, nullptr, nullptr, nullptr, (float*)d_out, CDIM, bfc2, xmid, 768);
}